// Round 1
// baseline (10596.277 us; speedup 1.0000x reference)
//
#include <hip/hip_runtime.h>
#include <math.h>

// ---------------------------------------------------------------------------
// Transformer_fPEPS: transformer (f32 VALU GEMMs) + PEPS amplitude.
//
// Math reduction (verified by rank-tracing the reference _compress):
// every SVD in the reference is lossless gauge EXCEPT the bond-(2,3)
// truncation (64 -> chi=16) in the final compress of each side. Hence
//   amp(b) = < rank16(Psi_L), rank16(Psi_R) >_F
// with Psi_S the exact 64x64 half-overlap matrices of the 3x3 site blocks.
// rank16 via one-sided Jacobi (wave-per-matrix, registers, __shfl exchange).
// ---------------------------------------------------------------------------

#define BSZ   2048
#define NS    36
#define EMB   128
#define NHEAD 8
#define DH    16
#define HIDD  512
#define TOTV  10368

__constant__ int c_offs[37] = {
    0,32,160,288,416,544,576,
    704,1216,1728,2240,2752,2880,
    3008,3520,4032,4544,5056,5184,
    5312,5824,6336,6848,7360,7488,
    7616,8128,8640,9152,9664,9792,
    9824,9952,10080,10208,10336,10368};

// ------------------------------ K1: embed ----------------------------------
__global__ __launch_bounds__(256) void k_embed(const int* __restrict__ x,
        const float* __restrict__ emb, const float* __restrict__ pos,
        float* __restrict__ h) {
    int idx = blockIdx.x * 256 + threadIdx.x;
    if (idx >= BSZ * NS * EMB) return;
    int e = idx & (EMB - 1);
    int g = idx >> 7;            // token
    int s = g % NS;
    h[idx] = emb[x[g] * EMB + e] + pos[s * EMB + e];
}

// ------------------------------ K2: attention ------------------------------
__global__ __launch_bounds__(256) void k_attn(const float* __restrict__ hbuf,
        const float* __restrict__ Wqkv, const float* __restrict__ bqkv,
        const float* __restrict__ Wo, const float* __restrict__ bo,
        float* __restrict__ hout) {
    __shared__ float sh[NS][EMB];        // 18 KB
    __shared__ float skv[NS][2 * EMB];   // 36 KB (k | v), later reused for o
    int b = blockIdx.x, tid = threadIdx.x;
    const float* hb = hbuf + (size_t)b * NS * EMB;
    for (int i = tid; i < NS * EMB; i += 256) sh[i >> 7][i & 127] = hb[i];
    __syncthreads();
    // k and v for all 36 tokens
    for (int i = tid; i < NS * 2 * EMB; i += 256) {
        int s = i >> 8, c = i & 255;
        float acc = bqkv[EMB + c];
        const float* wcol = Wqkv + EMB + c;
        for (int e = 0; e < EMB; ++e) acc += sh[s][e] * wcol[e * 384];
        skv[s][c] = acc;
    }
    __syncthreads();
    float ov[2][DH];
    #pragma unroll
    for (int rep = 0; rep < 2; ++rep) {
        int pid = tid + rep * 256;
        if (pid < NHEAD * NS) {
            int hd = pid / NS, qp = pid % NS;
            float qv[DH];
            #pragma unroll
            for (int d = 0; d < DH; ++d) {
                float acc = bqkv[hd * DH + d];
                for (int e = 0; e < EMB; ++e)
                    acc += sh[qp][e] * Wqkv[e * 384 + hd * DH + d];
                qv[d] = acc;
            }
            float sc[NS];
            float mx = -1e30f;
            for (int j = 0; j < NS; ++j) {
                float acc = 0.f;
                #pragma unroll
                for (int d = 0; d < DH; ++d) acc += qv[d] * skv[j][hd * DH + d];
                sc[j] = acc * 0.25f;            // 1/sqrt(16)
                mx = fmaxf(mx, sc[j]);
            }
            float z = 0.f;
            for (int j = 0; j < NS; ++j) { sc[j] = expf(sc[j] - mx); z += sc[j]; }
            float inv = 1.f / z;
            #pragma unroll
            for (int d = 0; d < DH; ++d) {
                float acc = 0.f;
                for (int j = 0; j < NS; ++j) acc += sc[j] * skv[j][EMB + hd * DH + d];
                ov[rep][d] = acc * inv;
            }
        }
    }
    __syncthreads();   // everyone done reading k/v
    float (*so)[EMB] = (float(*)[EMB])skv;
    #pragma unroll
    for (int rep = 0; rep < 2; ++rep) {
        int pid = tid + rep * 256;
        if (pid < NHEAD * NS) {
            int hd = pid / NS, qp = pid % NS;
            #pragma unroll
            for (int d = 0; d < DH; ++d) so[qp][hd * DH + d] = ov[rep][d];
        }
    }
    __syncthreads();
    float* ho = hout + (size_t)b * NS * EMB;
    for (int i = tid; i < NS * EMB; i += 256) {
        int s = i >> 7, e = i & 127;
        float acc = sh[s][e] + bo[e];
        for (int f = 0; f < EMB; ++f) acc += so[s][f] * Wo[f * EMB + e];
        ho[i] = acc;
    }
}

// ------------------------------ K3: MLP + backflow -------------------------
// 32 tokens per block; raw = gelu(h@W1+b1)@W2+b2; vecs = ftn + 0.1*raw[:size]
__global__ __launch_bounds__(256) void k_mlp(const float* __restrict__ hbuf,
        const float* __restrict__ W1, const float* __restrict__ b1,
        const float* __restrict__ W2, const float* __restrict__ b2,
        const float* __restrict__ ftn, float* __restrict__ vecs) {
    __shared__ float hv[32][EMB];   // 16 KB
    __shared__ float hc[32][32];    // 4 KB
    int tid = threadIdx.x;
    int tok0 = blockIdx.x * 32;
    for (int i = tid; i < 32 * EMB; i += 256)
        hv[i >> 7][i & 127] = hbuf[(size_t)tok0 * EMB + i];
    __syncthreads();
    int tp = tid >> 4;   // token pair 0..15 -> tokens 2tp, 2tp+1
    int cg = tid & 15;   // col group -> cols cg*32 .. +31
    float acc[2][32];
    #pragma unroll
    for (int c = 0; c < 32; ++c) { acc[0][c] = 0.f; acc[1][c] = 0.f; }
    for (int kc = 0; kc < 16; ++kc) {
        for (int i = tid; i < 32 * 32; i += 256) {
            int s = i >> 5, kk = i & 31;
            int col = kc * 32 + kk;
            float a = b1[col];
            for (int e = 0; e < EMB; ++e) a += hv[s][e] * W1[e * HIDD + col];
            hc[s][kk] = 0.5f * a * (1.f + erff(a * 0.70710678118654752f));
        }
        __syncthreads();
        for (int kk = 0; kk < 32; ++kk) {
            const float4* w4 = (const float4*)(W2 + (size_t)(kc * 32 + kk) * HIDD + cg * 32);
            float h0 = hc[tp * 2][kk], h1 = hc[tp * 2 + 1][kk];
            #pragma unroll
            for (int cq = 0; cq < 8; ++cq) {
                float4 w = w4[cq];
                acc[0][cq*4+0] += h0 * w.x; acc[0][cq*4+1] += h0 * w.y;
                acc[0][cq*4+2] += h0 * w.z; acc[0][cq*4+3] += h0 * w.w;
                acc[1][cq*4+0] += h1 * w.x; acc[1][cq*4+1] += h1 * w.y;
                acc[1][cq*4+2] += h1 * w.z; acc[1][cq*4+3] += h1 * w.w;
            }
        }
        __syncthreads();
    }
    #pragma unroll
    for (int ti = 0; ti < 2; ++ti) {
        int tok = tok0 + tp * 2 + ti;
        int b = tok / NS, s = tok - b * NS;
        int off = c_offs[s], sz = c_offs[s + 1] - off;
        for (int c = 0; c < 32; ++c) {
            int col = cg * 32 + c;
            if (col < sz) {
                float o = acc[ti][c] + b2[col];
                vecs[(size_t)b * TOTV + off + col] = ftn[off + col] + 0.1f * o;
            }
        }
    }
}

// ------------------------------ K4a: build Psi -----------------------------
// Block m: b = m>>1, side = m&1 (0=left cols 0..2, 1=right cols 5..3).
// Builds A (rows 0-2) and Bt (rows 5-3) 64x64 tensors then Psi = A Bt^T.
__device__ __forceinline__ float* build_half(const float* __restrict__ vb,
        const int* __restrict__ xb, int side, int upper,
        float* cur, float* fre, float* ts0, float* ts1, float* ts2, int tid) {
    if (tid == 0) cur[0] = 1.0f;
    __syncthreads();
    int bd = 1, lgbd = 0;
    for (int t = 0; t < 3; ++t) {
        int xd = t ? 4 : 1, lgxd = t ? 2 : 0;
        int j = side ? (5 - t) : t;
        int rows[3];
        rows[0] = upper ? 0 : 5; rows[1] = upper ? 1 : 4; rows[2] = upper ? 2 : 3;
        // load the 3 role tensors of this column
        for (int role = 0; role < 3; ++role) {
            int i = rows[role];
            int dd = (i < 5) ? 4 : 1, dl = (j > 0) ? 4 : 1, dr = (j < 5) ? 4 : 1;
            int su = dd * dl * dr * 2, sd = dl * dr * 2, sl = dr * 2, sr = 2;
            int xstr = side ? sr : sl, ystr = side ? sl : sr;
            int base = c_offs[i * 6 + j] + xb[i * 6 + j];
            if (role == 0) {
                int astr = upper ? sd : su;
                int n = 4 * xd * 4;
                for (int idx = tid; idx < n; idx += 256) {
                    int y = idx & 3, xx = (idx >> 2) & (xd - 1), a = idx >> (2 + lgxd);
                    ts0[idx] = vb[base + a * astr + xx * xstr + y * ystr];
                }
            } else if (role == 1) {
                int astr = upper ? su : sd, cstr = upper ? sd : su;
                int n = 16 * xd * 4;
                for (int idx = tid; idx < n; idx += 256) {
                    int y = idx & 3, xx = (idx >> 2) & (xd - 1);
                    int c = (idx >> (2 + lgxd)) & 3, a = idx >> (4 + lgxd);
                    ts1[idx] = vb[base + a * astr + c * cstr + xx * xstr + y * ystr];
                }
            } else {
                int cstr = upper ? su : sd, bstr = upper ? sd : su;
                int n = 16 * xd * 4;
                for (int idx = tid; idx < n; idx += 256) {
                    int y = idx & 3, xx = (idx >> 2) & (xd - 1);
                    int bb = (idx >> (2 + lgxd)) & 3, c = idx >> (4 + lgxd);
                    ts2[idx] = vb[base + c * cstr + bb * bstr + xx * xstr + y * ystr];
                }
            }
        }
        __syncthreads();
        // U1[y0][a][x1][x2][beta] = sum_x0 S[x0,x1,x2,beta]*t0[a,x0,y0]  -> fre
        int n1 = 16 * xd * xd * bd;
        for (int idx = tid; idx < n1; idx += 256) {
            int bt = idx & (bd - 1);
            int r = idx >> lgbd;
            int x2 = r & (xd - 1); r >>= lgxd;
            int x1 = r & (xd - 1); r >>= lgxd;
            int a = r & 3, y0 = r >> 2;
            float s2 = 0.f;
            for (int x0 = 0; x0 < xd; ++x0)
                s2 += cur[(((((x0 << lgxd) | x1) << lgxd) | x2) << lgbd) | bt]
                    * ts0[(((a << lgxd) | x0) << 2) | y0];
            fre[idx] = s2;
        }
        __syncthreads();
        // U2[y0][y1][c][x2][beta] = sum_{a,x1} U1 * t1[a,c,x1,y1]  -> cur
        int n2 = 64 * xd * bd;
        for (int idx = tid; idx < n2; idx += 256) {
            int bt = idx & (bd - 1);
            int r = idx >> lgbd;
            int x2 = r & (xd - 1); r >>= lgxd;
            int c = r & 3, y1 = (r >> 2) & 3, y0 = r >> 4;
            float s2 = 0.f;
            for (int a = 0; a < 4; ++a)
                for (int x1 = 0; x1 < xd; ++x1)
                    s2 += fre[((((((((y0 << 2) | a) << lgxd) | x1) << lgxd) | x2)) << lgbd) | bt]
                        * ts1[((((a * 4 + c) << lgxd) | x1) << 2) | y1];
            cur[idx] = s2;
        }
        __syncthreads();
        // S'[y0][y1][y2][beta*4+b] = sum_{c,x2} U2 * t2[c,b,x2,y2]  -> fre
        int n3 = 256 * bd;
        for (int idx = tid; idx < n3; idx += 256) {
            int bn = idx & (4 * bd - 1);
            int bt = bn >> 2, bb = bn & 3;
            int r = idx >> (lgbd + 2);
            int y2 = r & 3, y1 = (r >> 2) & 3, y0 = r >> 4;
            float s2 = 0.f;
            for (int c = 0; c < 4; ++c)
                for (int x2 = 0; x2 < xd; ++x2)
                    s2 += cur[((((((y0 << 2) | y1) << 2 | c) << lgxd) | x2) << lgbd) | bt]
                        * ts2[((((c * 4 + bb) << lgxd) | x2) << 2) | y2];
            fre[idx] = s2;
        }
        __syncthreads();
        float* tmp = cur; cur = fre; fre = tmp;
        bd <<= 2; lgbd += 2;
    }
    return cur;
}

__global__ __launch_bounds__(256) void k_build(const float* __restrict__ vecs,
        const int* __restrict__ x, float* __restrict__ psi) {
    __shared__ float X1[4096], X2[4096], X3[4096];
    __shared__ float ts0[64], ts1[256], ts2[256];
    int m = blockIdx.x;
    int b = m >> 1, side = m & 1;
    int tid = threadIdx.x;
    const float* vb = vecs + (size_t)b * TOTV;
    const int* xb = x + b * NS;
    float* A  = build_half(vb, xb, side, 1, X1, X2, ts0, ts1, ts2, tid); // ends in X2
    float* Bt = build_half(vb, xb, side, 0, X1, X3, ts0, ts1, ts2, tid); // ends in X3
    float* po = psi + (size_t)m * 4096;
    for (int idx = tid; idx < 4096; idx += 256) {
        int u = idx >> 6, l = idx & 63;
        const float4* a4 = (const float4*)(A + u * 64);
        const float4* b4 = (const float4*)(Bt + l * 64);
        float s2 = 0.f;
        #pragma unroll
        for (int q = 0; q < 16; ++q) {
            float4 av = a4[q], bv = b4[q];
            s2 += av.x * bv.x + av.y * bv.y + av.z * bv.z + av.w * bv.w;
        }
        po[idx] = s2;
    }
}

// ------------------------------ K4b: Jacobi SVD ----------------------------
// One wave per 64x64 matrix. Lane j holds column j of W (=Psi*V) and V.
// Keeps top-16 columns by norm; writes W16|V16 (2048 floats) per matrix.
__global__ __launch_bounds__(256) void k_svd(const float* __restrict__ psi,
                                             float* __restrict__ wv) {
    int m = blockIdx.x * 4 + (threadIdx.x >> 6);
    int lane = threadIdx.x & 63;
    const float* P = psi + (size_t)m * 4096;
    float W[64], V[64];
    #pragma unroll
    for (int r = 0; r < 64; ++r) {
        W[r] = P[r * 64 + lane];
        V[r] = (r == lane) ? 1.f : 0.f;
    }
    for (int sweep = 0; sweep < 10; ++sweep) {
        bool any = false;
        for (int mm = 1; mm < 64; ++mm) {
            int partner = lane ^ mm;
            float pw[64];
            float alpha = 0.f, gam = 0.f;
            #pragma unroll
            for (int r = 0; r < 64; ++r) {
                pw[r] = __shfl(W[r], partner);
                alpha += W[r] * W[r];
                gam   += W[r] * pw[r];
            }
            float beta2 = __shfl(alpha, partner);
            bool rot = fabsf(gam) > 1e-8f * sqrtf(alpha) * sqrtf(beta2);
            unsigned long long bal = __ballot(rot);
            if (bal == 0ull) continue;
            any = true;
            float c = 1.f, s = 0.f;
            if (rot) {
                float zeta = (alpha - beta2) / (2.f * gam);
                float sgn = (zeta > 0.f) ? 1.f :
                            ((zeta < 0.f) ? -1.f : ((lane < partner) ? 1.f : -1.f));
                float tt = sgn / (fabsf(zeta) + sqrtf(1.f + zeta * zeta));
                c = 1.f / sqrtf(1.f + tt * tt);
                s = c * tt;
            }
            #pragma unroll
            for (int r = 0; r < 64; ++r) W[r] = c * W[r] + s * pw[r];
            #pragma unroll
            for (int r = 0; r < 64; ++r) {
                float pv = __shfl(V[r], partner);
                V[r] = c * V[r] + s * pv;
            }
        }
        if (!any) break;
    }
    float n2 = 0.f;
    #pragma unroll
    for (int r = 0; r < 64; ++r) n2 += W[r] * W[r];
    int rank = 0;
    for (int j = 0; j < 64; ++j) {
        float nj = __shfl(n2, j);
        if (nj > n2 || (nj == n2 && j < lane)) ++rank;
    }
    if (rank < 16) {
        float* o = wv + (size_t)m * 2048 + rank * 64;
        #pragma unroll
        for (int r = 0; r < 64; ++r) o[r] = W[r];
        o += 1024;
        #pragma unroll
        for (int r = 0; r < 64; ++r) o[r] = V[r];
    }
}

// ------------------------------ K4c: amplitude -----------------------------
__global__ __launch_bounds__(256) void k_amp(const float* __restrict__ wv,
                                             float* __restrict__ out) {
    __shared__ float s[4096];
    __shared__ float part[4];
    int b = blockIdx.x, tid = threadIdx.x;
    const float* src = wv + (size_t)b * 4096;
    for (int i = tid; i < 4096; i += 256) s[i] = src[i];
    __syncthreads();
    int k = tid >> 4, mm = tid & 15;
    const float* WL = s;
    const float* VL = s + 1024;
    const float* WR = s + 2048;
    const float* VR = s + 3072;
    float du = 0.f, dv = 0.f;
    for (int r = 0; r < 64; ++r) {
        du += WL[k * 64 + r] * WR[mm * 64 + r];
        dv += VL[k * 64 + r] * VR[mm * 64 + r];
    }
    float p = du * dv;
    for (int off = 32; off > 0; off >>= 1) p += __shfl_down(p, off);
    if ((tid & 63) == 0) part[tid >> 6] = p;
    __syncthreads();
    if (tid == 0) out[b] = part[0] + part[1] + part[2] + part[3];
}

// ------------------------------ launch -------------------------------------
extern "C" void kernel_launch(void* const* d_in, const int* in_sizes, int n_in,
                              void* d_out, int out_size, void* d_ws, size_t ws_size,
                              hipStream_t stream) {
    const int*   x    = (const int*)d_in[0];
    const float* ftn  = (const float*)d_in[1];
    const float* emb  = (const float*)d_in[2];
    const float* pos  = (const float*)d_in[3];
    const float* Wqkv = (const float*)d_in[4];
    const float* bqkv = (const float*)d_in[5];
    const float* Wo   = (const float*)d_in[6];
    const float* bo   = (const float*)d_in[7];
    const float* W1   = (const float*)d_in[8];
    const float* b1   = (const float*)d_in[9];
    const float* W2   = (const float*)d_in[10];
    const float* b2   = (const float*)d_in[11];
    float* out = (float*)d_out;
    float* ws  = (float*)d_ws;

    // layout (floats): [h | psi alias: 16777216][vecs: 21233664][wv: 8388608]
    float* h    = ws;                    // 2048*36*128 = 9437184 (dead after K3)
    float* psi  = ws;                    // 4096*4096  = 16777216 (after K3)
    float* vecs = ws + 16777216;
    float* wv   = ws + 16777216 + 21233664;

    hipLaunchKernelGGL(k_embed, dim3((BSZ * NS * EMB + 255) / 256), dim3(256), 0, stream,
                       x, emb, pos, h);
    hipLaunchKernelGGL(k_attn, dim3(BSZ), dim3(256), 0, stream,
                       h, Wqkv, bqkv, Wo, bo, h);
    hipLaunchKernelGGL(k_mlp, dim3(BSZ * NS / 32), dim3(256), 0, stream,
                       h, W1, b1, W2, b2, ftn, vecs);
    hipLaunchKernelGGL(k_build, dim3(2 * BSZ), dim3(256), 0, stream, vecs, x, psi);
    hipLaunchKernelGGL(k_svd, dim3(BSZ / 2), dim3(256), 0, stream, psi, wv);
    hipLaunchKernelGGL(k_amp, dim3(BSZ), dim3(256), 0, stream, wv, out);
}

// Round 2
// 6846.070 us; speedup vs baseline: 1.5478x; 1.5478x over previous
//
#include <hip/hip_runtime.h>
#include <math.h>

// ---------------------------------------------------------------------------
// Transformer_fPEPS: transformer (f32 VALU GEMMs) + PEPS amplitude.
//
// Math reduction (validated R1, absmax 3.8e-6): every SVD in the reference
// _compress is lossless gauge EXCEPT the bond-(2,3) truncation (64 -> chi=16)
// on each side. amp(b) = < rank16(Psi_L), rank16(Psi_R) >_F.
//
// R2: replace latency-bound k_mlp (5.07 ms, VALUBusy 10%) with register-tiled
// LDS-staged GEMMs; trim GEMM2 to needed site columns (sizes {32,128,512});
// batch-split x8 so the Hm slab reuses the psi region (footprint stays 186MB).
// ---------------------------------------------------------------------------

#define BSZ   2048
#define NS    36
#define EMB   128
#define NHEAD 8
#define DH    16
#define HIDD  512
#define TOTV  10368

__constant__ int c_offs[37] = {
    0,32,160,288,416,544,576,
    704,1216,1728,2240,2752,2880,
    3008,3520,4032,4544,5056,5184,
    5312,5824,6336,6848,7360,7488,
    7616,8128,8640,9152,9664,9792,
    9824,9952,10080,10208,10336,10368};

// (site, col-chunk) pairs for trimmed GEMM2: 84 pairs
__constant__ int c_ps[84] = {
    0,1,2,3,4,5,
    6,7,7,7,7,8,8,8,8,9,9,9,9,10,10,10,10,11,
    12,13,13,13,13,14,14,14,14,15,15,15,15,16,16,16,16,17,
    18,19,19,19,19,20,20,20,20,21,21,21,21,22,22,22,22,23,
    24,25,25,25,25,26,26,26,26,27,27,27,27,28,28,28,28,29,
    30,31,32,33,34,35};
__constant__ int c_pc[84] = {
    0,0,0,0,0,0,
    0,0,1,2,3,0,1,2,3,0,1,2,3,0,1,2,3,0,
    0,0,1,2,3,0,1,2,3,0,1,2,3,0,1,2,3,0,
    0,0,1,2,3,0,1,2,3,0,1,2,3,0,1,2,3,0,
    0,0,1,2,3,0,1,2,3,0,1,2,3,0,1,2,3,0,
    0,0,0,0,0,0};

// ------------------------------ K1: embed ----------------------------------
__global__ __launch_bounds__(256) void k_embed(const int* __restrict__ x,
        const float* __restrict__ emb, const float* __restrict__ pos,
        float* __restrict__ h) {
    int idx = blockIdx.x * 256 + threadIdx.x;
    if (idx >= BSZ * NS * EMB) return;
    int e = idx & (EMB - 1);
    int g = idx >> 7;            // token
    int s = g % NS;
    h[idx] = emb[x[g] * EMB + e] + pos[s * EMB + e];
}

// ------------------------------ K2: attention ------------------------------
__global__ __launch_bounds__(256) void k_attn(const float* __restrict__ hbuf,
        const float* __restrict__ Wqkv, const float* __restrict__ bqkv,
        const float* __restrict__ Wo, const float* __restrict__ bo,
        float* __restrict__ hout) {
    __shared__ float sh[NS][EMB];        // 18 KB
    __shared__ float skv[NS][2 * EMB];   // 36 KB (k | v), later reused for o
    int b = blockIdx.x, tid = threadIdx.x;
    const float* hb = hbuf + (size_t)b * NS * EMB;
    for (int i = tid; i < NS * EMB; i += 256) sh[i >> 7][i & 127] = hb[i];
    __syncthreads();
    // k and v for all 36 tokens
    for (int i = tid; i < NS * 2 * EMB; i += 256) {
        int s = i >> 8, c = i & 255;
        float acc = bqkv[EMB + c];
        const float* wcol = Wqkv + EMB + c;
        for (int e = 0; e < EMB; ++e) acc += sh[s][e] * wcol[e * 384];
        skv[s][c] = acc;
    }
    __syncthreads();
    float ov[2][DH];
    #pragma unroll
    for (int rep = 0; rep < 2; ++rep) {
        int pid = tid + rep * 256;
        if (pid < NHEAD * NS) {
            int hd = pid / NS, qp = pid % NS;
            float qv[DH];
            #pragma unroll
            for (int d = 0; d < DH; ++d) {
                float acc = bqkv[hd * DH + d];
                for (int e = 0; e < EMB; ++e)
                    acc += sh[qp][e] * Wqkv[e * 384 + hd * DH + d];
                qv[d] = acc;
            }
            float sc[NS];
            float mx = -1e30f;
            for (int j = 0; j < NS; ++j) {
                float acc = 0.f;
                #pragma unroll
                for (int d = 0; d < DH; ++d) acc += qv[d] * skv[j][hd * DH + d];
                sc[j] = acc * 0.25f;            // 1/sqrt(16)
                mx = fmaxf(mx, sc[j]);
            }
            float z = 0.f;
            for (int j = 0; j < NS; ++j) { sc[j] = expf(sc[j] - mx); z += sc[j]; }
            float inv = 1.f / z;
            #pragma unroll
            for (int d = 0; d < DH; ++d) {
                float acc = 0.f;
                for (int j = 0; j < NS; ++j) acc += sc[j] * skv[j][EMB + hd * DH + d];
                ov[rep][d] = acc * inv;
            }
        }
    }
    __syncthreads();   // everyone done reading k/v
    float (*so)[EMB] = (float(*)[EMB])skv;
    #pragma unroll
    for (int rep = 0; rep < 2; ++rep) {
        int pid = tid + rep * 256;
        if (pid < NHEAD * NS) {
            int hd = pid / NS, qp = pid % NS;
            #pragma unroll
            for (int d = 0; d < DH; ++d) so[qp][hd * DH + d] = ov[rep][d];
        }
    }
    __syncthreads();
    float* ho = hout + (size_t)b * NS * EMB;
    for (int i = tid; i < NS * EMB; i += 256) {
        int s = i >> 7, e = i & 127;
        float acc = sh[s][e] + bo[e];
        for (int f = 0; f < EMB; ++f) acc += so[s][f] * Wo[f * EMB + e];
        ho[i] = acc;
    }
}

// ------------------------------ K3a: GEMM1 (h@W1, gelu) --------------------
// Per block: 64 tokens x 128 cols, K=128. Thread tile 4 tokens x 8 cols.
// h is offset per batch-eighth; Hm_e is the per-eighth hidden slab.
__global__ __launch_bounds__(256) void k_gemm1(const float* __restrict__ h,
        const float* __restrict__ W1, const float* __restrict__ b1,
        float* __restrict__ Hm) {
    __shared__ float As[64 * 132];   // [token][k], pad 132
    __shared__ float Ws[32 * 132];   // [kk][col], pad 132
    int tid = threadIdx.x;
    int chunk = blockIdx.x;          // 0..3 -> output cols chunk*128..+127
    int tok0 = blockIdx.y * 64;      // token tile (local to eighth)
    int tx = tid & 15, ty = tid >> 4;
    for (int idx = tid; idx < 64 * 128; idx += 256) {
        int t = idx >> 7, k = idx & 127;
        As[t * 132 + k] = h[(size_t)(tok0 + t) * EMB + k];
    }
    float acc[4][8];
    #pragma unroll
    for (int i = 0; i < 4; ++i)
        #pragma unroll
        for (int q = 0; q < 8; ++q) acc[i][q] = 0.f;
    for (int ks = 0; ks < 4; ++ks) {
        __syncthreads();
        for (int idx = tid; idx < 32 * 128; idx += 256) {
            int kk = idx >> 7, c = idx & 127;
            Ws[kk * 132 + c] = W1[(size_t)(ks * 32 + kk) * HIDD + chunk * 128 + c];
        }
        __syncthreads();
        #pragma unroll 4
        for (int kk = 0; kk < 32; ++kk) {
            float4 w0 = *(const float4*)&Ws[kk * 132 + tx * 8];
            float4 w1 = *(const float4*)&Ws[kk * 132 + tx * 8 + 4];
            #pragma unroll
            for (int i = 0; i < 4; ++i) {
                float a = As[(ty * 4 + i) * 132 + ks * 32 + kk];
                acc[i][0] += a * w0.x; acc[i][1] += a * w0.y;
                acc[i][2] += a * w0.z; acc[i][3] += a * w0.w;
                acc[i][4] += a * w1.x; acc[i][5] += a * w1.y;
                acc[i][6] += a * w1.z; acc[i][7] += a * w1.w;
            }
        }
    }
    #pragma unroll
    for (int i = 0; i < 4; ++i) {
        size_t base = (size_t)(tok0 + ty * 4 + i) * HIDD + chunk * 128 + tx * 8;
        #pragma unroll
        for (int q = 0; q < 8; ++q) {
            float a = acc[i][q] + b1[chunk * 128 + tx * 8 + q];
            Hm[base + q] = 0.5f * a * (1.f + erff(a * 0.70710678118654752f));
        }
    }
}

// ------------------------------ K3b: GEMM2 (Hm@W2, backflow) ---------------
// Grid: (84 site-chunk pairs) x (4 batch tiles of 64). K=512 in 16 slices.
// Thread tile 4 batches x 8 cols. Only needed site columns are computed.
__global__ __launch_bounds__(256) void k_gemm2(const float* __restrict__ Hm,
        const float* __restrict__ W2, const float* __restrict__ b2,
        const float* __restrict__ ftn, float* __restrict__ vecs, int e8) {
    __shared__ float As[64 * 33];    // [batch][kk], pad 33
    __shared__ float Ws[32 * 132];   // [kk][col], pad 132
    int tid = threadIdx.x;
    int pair = blockIdx.x;
    int s = c_ps[pair], chunk = c_pc[pair];
    int b0 = blockIdx.y * 64;        // batch tile (local to eighth)
    int off = c_offs[s], size = c_offs[s + 1] - off;
    int tx = tid & 15, ty = tid >> 4;
    float acc[4][8];
    #pragma unroll
    for (int i = 0; i < 4; ++i)
        #pragma unroll
        for (int q = 0; q < 8; ++q) acc[i][q] = 0.f;
    for (int ks = 0; ks < 16; ++ks) {
        __syncthreads();
        for (int idx = tid; idx < 64 * 32; idx += 256) {
            int t = idx >> 5, kk = idx & 31;
            As[t * 33 + kk] = Hm[(size_t)((b0 + t) * NS + s) * HIDD + ks * 32 + kk];
        }
        for (int idx = tid; idx < 32 * 128; idx += 256) {
            int kk = idx >> 7, c = idx & 127;
            Ws[kk * 132 + c] = W2[(size_t)(ks * 32 + kk) * HIDD + chunk * 128 + c];
        }
        __syncthreads();
        #pragma unroll 4
        for (int kk = 0; kk < 32; ++kk) {
            float4 w0 = *(const float4*)&Ws[kk * 132 + tx * 8];
            float4 w1 = *(const float4*)&Ws[kk * 132 + tx * 8 + 4];
            #pragma unroll
            for (int i = 0; i < 4; ++i) {
                float a = As[(ty * 4 + i) * 33 + kk];
                acc[i][0] += a * w0.x; acc[i][1] += a * w0.y;
                acc[i][2] += a * w0.z; acc[i][3] += a * w0.w;
                acc[i][4] += a * w1.x; acc[i][5] += a * w1.y;
                acc[i][6] += a * w1.z; acc[i][7] += a * w1.w;
            }
        }
    }
    #pragma unroll
    for (int i = 0; i < 4; ++i) {
        int bg = e8 * 256 + b0 + ty * 4 + i;     // global batch
        #pragma unroll
        for (int q = 0; q < 8; ++q) {
            int col = chunk * 128 + tx * 8 + q;
            if (col < size) {
                float o = acc[i][q] + b2[col];
                vecs[(size_t)bg * TOTV + off + col] = ftn[off + col] + 0.1f * o;
            }
        }
    }
}

// ------------------------------ K4a: build Psi -----------------------------
__device__ __forceinline__ float* build_half(const float* __restrict__ vb,
        const int* __restrict__ xb, int side, int upper,
        float* cur, float* fre, float* ts0, float* ts1, float* ts2, int tid) {
    if (tid == 0) cur[0] = 1.0f;
    __syncthreads();
    int bd = 1, lgbd = 0;
    for (int t = 0; t < 3; ++t) {
        int xd = t ? 4 : 1, lgxd = t ? 2 : 0;
        int j = side ? (5 - t) : t;
        int rows[3];
        rows[0] = upper ? 0 : 5; rows[1] = upper ? 1 : 4; rows[2] = upper ? 2 : 3;
        for (int role = 0; role < 3; ++role) {
            int i = rows[role];
            int dd = (i < 5) ? 4 : 1, dl = (j > 0) ? 4 : 1, dr = (j < 5) ? 4 : 1;
            int su = dd * dl * dr * 2, sd = dl * dr * 2, sl = dr * 2, sr = 2;
            int xstr = side ? sr : sl, ystr = side ? sl : sr;
            int base = c_offs[i * 6 + j] + xb[i * 6 + j];
            if (role == 0) {
                int astr = upper ? sd : su;
                int n = 4 * xd * 4;
                for (int idx = tid; idx < n; idx += 256) {
                    int y = idx & 3, xx = (idx >> 2) & (xd - 1), a = idx >> (2 + lgxd);
                    ts0[idx] = vb[base + a * astr + xx * xstr + y * ystr];
                }
            } else if (role == 1) {
                int astr = upper ? su : sd, cstr = upper ? sd : su;
                int n = 16 * xd * 4;
                for (int idx = tid; idx < n; idx += 256) {
                    int y = idx & 3, xx = (idx >> 2) & (xd - 1);
                    int c = (idx >> (2 + lgxd)) & 3, a = idx >> (4 + lgxd);
                    ts1[idx] = vb[base + a * astr + c * cstr + xx * xstr + y * ystr];
                }
            } else {
                int cstr = upper ? su : sd, bstr = upper ? sd : su;
                int n = 16 * xd * 4;
                for (int idx = tid; idx < n; idx += 256) {
                    int y = idx & 3, xx = (idx >> 2) & (xd - 1);
                    int bb = (idx >> (2 + lgxd)) & 3, c = idx >> (4 + lgxd);
                    ts2[idx] = vb[base + c * cstr + bb * bstr + xx * xstr + y * ystr];
                }
            }
        }
        __syncthreads();
        int n1 = 16 * xd * xd * bd;
        for (int idx = tid; idx < n1; idx += 256) {
            int bt = idx & (bd - 1);
            int r = idx >> lgbd;
            int x2 = r & (xd - 1); r >>= lgxd;
            int x1 = r & (xd - 1); r >>= lgxd;
            int a = r & 3, y0 = r >> 2;
            float s2 = 0.f;
            for (int x0 = 0; x0 < xd; ++x0)
                s2 += cur[(((((x0 << lgxd) | x1) << lgxd) | x2) << lgbd) | bt]
                    * ts0[(((a << lgxd) | x0) << 2) | y0];
            fre[idx] = s2;
        }
        __syncthreads();
        int n2 = 64 * xd * bd;
        for (int idx = tid; idx < n2; idx += 256) {
            int bt = idx & (bd - 1);
            int r = idx >> lgbd;
            int x2 = r & (xd - 1); r >>= lgxd;
            int c = r & 3, y1 = (r >> 2) & 3, y0 = r >> 4;
            float s2 = 0.f;
            for (int a = 0; a < 4; ++a)
                for (int x1 = 0; x1 < xd; ++x1)
                    s2 += fre[((((((((y0 << 2) | a) << lgxd) | x1) << lgxd) | x2)) << lgbd) | bt]
                        * ts1[((((a * 4 + c) << lgxd) | x1) << 2) | y1];
            cur[idx] = s2;
        }
        __syncthreads();
        int n3 = 256 * bd;
        for (int idx = tid; idx < n3; idx += 256) {
            int bn = idx & (4 * bd - 1);
            int bt = bn >> 2, bb = bn & 3;
            int r = idx >> (lgbd + 2);
            int y2 = r & 3, y1 = (r >> 2) & 3, y0 = r >> 4;
            float s2 = 0.f;
            for (int c = 0; c < 4; ++c)
                for (int x2 = 0; x2 < xd; ++x2)
                    s2 += cur[((((((y0 << 2) | y1) << 2 | c) << lgxd) | x2) << lgbd) | bt]
                        * ts2[((((c * 4 + bb) << lgxd) | x2) << 2) | y2];
            fre[idx] = s2;
        }
        __syncthreads();
        float* tmp = cur; cur = fre; fre = tmp;
        bd <<= 2; lgbd += 2;
    }
    return cur;
}

__global__ __launch_bounds__(256) void k_build(const float* __restrict__ vecs,
        const int* __restrict__ x, float* __restrict__ psi) {
    __shared__ float X1[4096], X2[4096], X3[4096];
    __shared__ float ts0[64], ts1[256], ts2[256];
    int m = blockIdx.x;
    int b = m >> 1, side = m & 1;
    int tid = threadIdx.x;
    const float* vb = vecs + (size_t)b * TOTV;
    const int* xb = x + b * NS;
    float* A  = build_half(vb, xb, side, 1, X1, X2, ts0, ts1, ts2, tid);
    float* Bt = build_half(vb, xb, side, 0, X1, X3, ts0, ts1, ts2, tid);
    float* po = psi + (size_t)m * 4096;
    for (int idx = tid; idx < 4096; idx += 256) {
        int u = idx >> 6, l = idx & 63;
        const float4* a4 = (const float4*)(A + u * 64);
        const float4* b4 = (const float4*)(Bt + l * 64);
        float s2 = 0.f;
        #pragma unroll
        for (int q = 0; q < 16; ++q) {
            float4 av = a4[q], bv = b4[q];
            s2 += av.x * bv.x + av.y * bv.y + av.z * bv.z + av.w * bv.w;
        }
        po[idx] = s2;
    }
}

// ------------------------------ K4b: Jacobi SVD ----------------------------
__global__ __launch_bounds__(256) void k_svd(const float* __restrict__ psi,
                                             float* __restrict__ wv) {
    int m = blockIdx.x * 4 + (threadIdx.x >> 6);
    int lane = threadIdx.x & 63;
    const float* P = psi + (size_t)m * 4096;
    float W[64], V[64];
    #pragma unroll
    for (int r = 0; r < 64; ++r) {
        W[r] = P[r * 64 + lane];
        V[r] = (r == lane) ? 1.f : 0.f;
    }
    for (int sweep = 0; sweep < 10; ++sweep) {
        bool any = false;
        for (int mm = 1; mm < 64; ++mm) {
            int partner = lane ^ mm;
            float pw[64];
            float alpha = 0.f, gam = 0.f;
            #pragma unroll
            for (int r = 0; r < 64; ++r) {
                pw[r] = __shfl(W[r], partner);
                alpha += W[r] * W[r];
                gam   += W[r] * pw[r];
            }
            float beta2 = __shfl(alpha, partner);
            bool rot = fabsf(gam) > 1e-8f * sqrtf(alpha) * sqrtf(beta2);
            unsigned long long bal = __ballot(rot);
            if (bal == 0ull) continue;
            any = true;
            float c = 1.f, s = 0.f;
            if (rot) {
                float zeta = (alpha - beta2) / (2.f * gam);
                float sgn = (zeta > 0.f) ? 1.f :
                            ((zeta < 0.f) ? -1.f : ((lane < partner) ? 1.f : -1.f));
                float tt = sgn / (fabsf(zeta) + sqrtf(1.f + zeta * zeta));
                c = 1.f / sqrtf(1.f + tt * tt);
                s = c * tt;
            }
            #pragma unroll
            for (int r = 0; r < 64; ++r) W[r] = c * W[r] + s * pw[r];
            #pragma unroll
            for (int r = 0; r < 64; ++r) {
                float pv = __shfl(V[r], partner);
                V[r] = c * V[r] + s * pv;
            }
        }
        if (!any) break;
    }
    float n2 = 0.f;
    #pragma unroll
    for (int r = 0; r < 64; ++r) n2 += W[r] * W[r];
    int rank = 0;
    for (int j = 0; j < 64; ++j) {
        float nj = __shfl(n2, j);
        if (nj > n2 || (nj == n2 && j < lane)) ++rank;
    }
    if (rank < 16) {
        float* o = wv + (size_t)m * 2048 + rank * 64;
        #pragma unroll
        for (int r = 0; r < 64; ++r) o[r] = W[r];
        o += 1024;
        #pragma unroll
        for (int r = 0; r < 64; ++r) o[r] = V[r];
    }
}

// ------------------------------ K4c: amplitude -----------------------------
__global__ __launch_bounds__(256) void k_amp(const float* __restrict__ wv,
                                             float* __restrict__ out) {
    __shared__ float s[4096];
    __shared__ float part[4];
    int b = blockIdx.x, tid = threadIdx.x;
    const float* src = wv + (size_t)b * 4096;
    for (int i = tid; i < 4096; i += 256) s[i] = src[i];
    __syncthreads();
    int k = tid >> 4, mm = tid & 15;
    const float* WL = s;
    const float* VL = s + 1024;
    const float* WR = s + 2048;
    const float* VR = s + 3072;
    float du = 0.f, dv = 0.f;
    for (int r = 0; r < 64; ++r) {
        du += WL[k * 64 + r] * WR[mm * 64 + r];
        dv += VL[k * 64 + r] * VR[mm * 64 + r];
    }
    float p = du * dv;
    for (int off = 32; off > 0; off >>= 1) p += __shfl_down(p, off);
    if ((tid & 63) == 0) part[tid >> 6] = p;
    __syncthreads();
    if (tid == 0) out[b] = part[0] + part[1] + part[2] + part[3];
}

// ------------------------------ launch -------------------------------------
extern "C" void kernel_launch(void* const* d_in, const int* in_sizes, int n_in,
                              void* d_out, int out_size, void* d_ws, size_t ws_size,
                              hipStream_t stream) {
    const int*   x    = (const int*)d_in[0];
    const float* ftn  = (const float*)d_in[1];
    const float* emb  = (const float*)d_in[2];
    const float* pos  = (const float*)d_in[3];
    const float* Wqkv = (const float*)d_in[4];
    const float* bqkv = (const float*)d_in[5];
    const float* Wo   = (const float*)d_in[6];
    const float* bo   = (const float*)d_in[7];
    const float* W1   = (const float*)d_in[8];
    const float* b1   = (const float*)d_in[9];
    const float* W2   = (const float*)d_in[10];
    const float* b2   = (const float*)d_in[11];
    float* out = (float*)d_out;
    float* ws  = (float*)d_ws;

    // layout (floats), total 46.4M = 186 MB (same as R1 proven footprint):
    //   [0, 16777216)           psi; h lives at [0, 9437184) (dead before psi),
    //                           Hm_e at [9437184, 14155776) (dead before psi)
    //   [16777216, 38010880)    vecs (2048*10368)
    //   [38010880, 46399488)    wv
    float* h    = ws;
    float* Hm_e = ws + 9437184;          // 2304 tokens * 512
    float* psi  = ws;
    float* vecs = ws + 16777216;
    float* wv   = ws + 16777216 + 21233664;

    hipLaunchKernelGGL(k_embed, dim3((BSZ * NS * EMB + 255) / 256), dim3(256), 0, stream,
                       x, emb, pos, h);
    hipLaunchKernelGGL(k_attn, dim3(BSZ), dim3(256), 0, stream,
                       h, Wqkv, bqkv, Wo, bo, h);
    // MLP in 8 batch-slices of 256 batches (9216 tokens) reusing Hm_e slab
    for (int e8 = 0; e8 < 8; ++e8) {
        const float* h_e = h + (size_t)e8 * 9216 * EMB;
        hipLaunchKernelGGL(k_gemm1, dim3(4, 144), dim3(256), 0, stream,
                           h_e, W1, b1, Hm_e);
        hipLaunchKernelGGL(k_gemm2, dim3(84, 4), dim3(256), 0, stream,
                           Hm_e, W2, b2, ftn, vecs, e8);
    }
    hipLaunchKernelGGL(k_build, dim3(2 * BSZ), dim3(256), 0, stream, vecs, x, psi);
    hipLaunchKernelGGL(k_svd, dim3(BSZ / 2), dim3(256), 0, stream, psi, wv);
    hipLaunchKernelGGL(k_amp, dim3(BSZ), dim3(256), 0, stream, wv, out);
}